// Round 1
// baseline (264.548 us; speedup 1.0000x reference)
//
#include <hip/hip_runtime.h>
#include <stdint.h>

typedef __attribute__((ext_vector_type(8))) short short8;     // 8 bf16 (4 VGPRs)
typedef __attribute__((ext_vector_type(4))) float f32x4;      // MFMA C/D
typedef __attribute__((ext_vector_type(4))) unsigned int uint4v; // 16B copy

#define DIMW 1024
#define HEADS 16
#define HEAD_DIM 64
#define SEQ 2048
#define BATCH 2
#define MTOK 4096
#define QKVN 3072

static __device__ __forceinline__ unsigned short f2bf(float f) {
    unsigned int u = __float_as_uint(f);
    u += 0x7fffu + ((u >> 16) & 1u);   // RNE; inputs are finite
    return (unsigned short)(u >> 16);
}

// ---------------- x: fp32 -> bf16 ----------------
__global__ void cast_x_kernel(const float* __restrict__ x, unsigned short* __restrict__ out) {
    int i = (blockIdx.x * 256 + threadIdx.x) * 8;
    float4 a = *(const float4*)(x + i);
    float4 b = *(const float4*)(x + i + 4);
    unsigned short t[8] = { f2bf(a.x), f2bf(a.y), f2bf(a.z), f2bf(a.w),
                            f2bf(b.x), f2bf(b.y), f2bf(b.z), f2bf(b.w) };
    *(uint4v*)(out + i) = *(const uint4v*)t;
}

// ---------------- W [K,N] fp32 -> Wt [N,K] bf16 (Wq|Wk|Wv fused, Wo separate) ----------------
__global__ void prep_w_kernel(const float* __restrict__ Wq, const float* __restrict__ Wk,
                              const float* __restrict__ Wv, const float* __restrict__ Wo,
                              unsigned short* __restrict__ Wqkv_t, unsigned short* __restrict__ Wo_t) {
    __shared__ float tile[64][68];
    int z = blockIdx.z;
    const float* W = (z == 0) ? Wq : (z == 1) ? Wk : (z == 2) ? Wv : Wo;
    unsigned short* out = (z < 3) ? (Wqkv_t + (size_t)z * DIMW * DIMW) : Wo_t;
    int n0 = blockIdx.x * 64, k0 = blockIdx.y * 64;
    int tid = threadIdx.x;
    for (int it = 0; it < 4; ++it) {                 // 1024 chunks of 4 floats
        int c = it * 256 + tid;
        int r = c >> 4, cg = c & 15;
        float4 v = *(const float4*)(W + (size_t)(k0 + r) * DIMW + n0 + cg * 4);
        tile[r][cg * 4 + 0] = v.x; tile[r][cg * 4 + 1] = v.y;
        tile[r][cg * 4 + 2] = v.z; tile[r][cg * 4 + 3] = v.w;
    }
    __syncthreads();
    for (int it = 0; it < 2; ++it) {                 // 512 chunks of 8 bf16
        int c = it * 256 + tid;
        int n = c >> 3, kg = c & 7;
        unsigned short tmp[8];
        #pragma unroll
        for (int j = 0; j < 8; ++j) tmp[j] = f2bf(tile[kg * 8 + j][n]);
        *(uint4v*)(out + (size_t)(n0 + n) * DIMW + k0 + kg * 8) = *(const uint4v*)tmp;
    }
}

// ---------------- GEMM: C[M,N] = A[M,K](bf16) * Bt[N,K]^T + bias ----------------
// QKV3: N=3072, bias selected from b0/b1/b2 per 1024-col section; Q section scaled by 0.125.
template<bool QKV3, typename TO>
__global__ __launch_bounds__(256, 2) void gemm_bt_kernel(
    const unsigned short* __restrict__ A, const unsigned short* __restrict__ Bt,
    const float* __restrict__ b0, const float* __restrict__ b1, const float* __restrict__ b2,
    TO* __restrict__ C, int M, int N, int K)
{
    __shared__ __align__(16) unsigned short As[128 * 40];  // [row][32 + 8 pad]
    __shared__ __align__(16) unsigned short Bs[128 * 40];
    int tid = threadIdx.x;
    int wave = tid >> 6, lane = tid & 63;
    int lrow = lane & 15, quad = lane >> 4;
    int bm = blockIdx.y * 128, bn = blockIdx.x * 128;
    int wm = (wave >> 1) * 64, wn = (wave & 1) * 64;
    f32x4 acc[4][4];
    #pragma unroll
    for (int i = 0; i < 4; ++i)
        #pragma unroll
        for (int j = 0; j < 4; ++j) acc[i][j] = (f32x4){0.f, 0.f, 0.f, 0.f};
    const unsigned short* Ap = A + (size_t)bm * K;
    const unsigned short* Bp = Bt + (size_t)bn * K;
    for (int k0 = 0; k0 < K; k0 += 32) {
        __syncthreads();
        #pragma unroll
        for (int it = 0; it < 2; ++it) {
            int c = it * 256 + tid;
            int row = c >> 2, cg = c & 3;
            *(uint4v*)&As[row * 40 + cg * 8] = *(const uint4v*)(Ap + (size_t)row * K + k0 + cg * 8);
            *(uint4v*)&Bs[row * 40 + cg * 8] = *(const uint4v*)(Bp + (size_t)row * K + k0 + cg * 8);
        }
        __syncthreads();
        short8 af[4], bfr[4];
        #pragma unroll
        for (int mi = 0; mi < 4; ++mi)
            af[mi] = *(const short8*)&As[(wm + mi * 16 + lrow) * 40 + quad * 8];
        #pragma unroll
        for (int ni = 0; ni < 4; ++ni)
            bfr[ni] = *(const short8*)&Bs[(wn + ni * 16 + lrow) * 40 + quad * 8];
        #pragma unroll
        for (int mi = 0; mi < 4; ++mi)
            #pragma unroll
            for (int ni = 0; ni < 4; ++ni)
                acc[mi][ni] = __builtin_amdgcn_mfma_f32_16x16x32_bf16(af[mi], bfr[ni], acc[mi][ni], 0, 0, 0);
    }
    #pragma unroll
    for (int ni = 0; ni < 4; ++ni) {
        int n = bn + wn + ni * 16 + lrow;
        float bias, scale;
        if (QKV3) {
            int sel = n >> 10;
            const float* bp = (sel == 0) ? b0 : (sel == 1) ? b1 : b2;
            bias = bp[n & 1023];
            scale = (sel == 0) ? 0.125f : 1.0f;   // fold 1/sqrt(64) into Q
        } else { bias = b0[n]; scale = 1.0f; }
        #pragma unroll
        for (int mi = 0; mi < 4; ++mi) {
            #pragma unroll
            for (int i = 0; i < 4; ++i) {
                int m = bm + wm + mi * 16 + quad * 4 + i;   // C/D: row=quad*4+reg, col=lane&15
                float val = (acc[mi][ni][i] + bias) * scale;
                if constexpr (sizeof(TO) == 2) C[(size_t)m * N + n] = (TO)f2bf(val);
                else                           C[(size_t)m * N + n] = val;
            }
        }
    }
}

// ---------------- V columns of QKV -> Vt [B*1024][2048] ----------------
__global__ void vt_kernel(const unsigned short* __restrict__ QKV, unsigned short* __restrict__ Vt) {
    __shared__ __align__(16) unsigned short tile[64][72];
    int s0 = blockIdx.x * 64, c0 = blockIdx.y * 64, b = blockIdx.z;
    int tid = threadIdx.x;
    const unsigned short* src = QKV + (size_t)(b * SEQ) * QKVN + 2048;
    for (int it = 0; it < 2; ++it) {
        int c = it * 256 + tid;
        int r = c >> 3, cg = c & 7;
        *(uint4v*)&tile[r][cg * 8] = *(const uint4v*)(src + (size_t)(s0 + r) * QKVN + c0 + cg * 8);
    }
    __syncthreads();
    for (int it = 0; it < 2; ++it) {
        int c = it * 256 + tid;
        int n = c >> 3, kg = c & 7;
        unsigned short tmp[8];
        #pragma unroll
        for (int j = 0; j < 8; ++j) tmp[j] = tile[kg * 8 + j][n];
        *(uint4v*)(Vt + (size_t)(b * 1024 + c0 + n) * SEQ + s0 + kg * 8) = *(const uint4v*)tmp;
    }
}

// ---------------- flash attention: 4 waves x 32 queries, 128-key stages ----------------
__global__ __launch_bounds__(256, 2) void attn_kernel(
    const unsigned short* __restrict__ QKV, const unsigned short* __restrict__ Vt,
    unsigned short* __restrict__ Emb)
{
    __shared__ __align__(16) unsigned short Ks[128 * 72];    // [key][d], pad 72
    __shared__ __align__(16) unsigned short Vs[64 * 136];    // [d][key], pad 136
    __shared__ __align__(16) unsigned short Ps[4][32 * 136]; // per-wave [q][key]
    int tid = threadIdx.x;
    int wave = tid >> 6, lane = tid & 63;
    int lrow = lane & 15, quad = lane >> 4;
    int qblk = blockIdx.x, h = blockIdx.y, b = blockIdx.z;
    int q0 = qblk * 128 + wave * 32;
    const unsigned short* Qbase = QKV + (size_t)(b * SEQ) * QKVN + h * 64;
    const unsigned short* Kbase = QKV + (size_t)(b * SEQ) * QKVN + 1024 + h * 64;
    const unsigned short* Vtb = Vt + (size_t)(b * 1024 + h * 64) * SEQ;

    short8 qf[2][2];   // A-frag: m=lane&15 (q), k=quad*8+j (d)
    #pragma unroll
    for (int mi = 0; mi < 2; ++mi)
        #pragma unroll
        for (int kc = 0; kc < 2; ++kc)
            qf[mi][kc] = *(const short8*)(Qbase + (size_t)(q0 + mi * 16 + lrow) * QKVN + kc * 32 + quad * 8);

    f32x4 o[2][4];
    f32x4 mrun[2], lrun[2];
    #pragma unroll
    for (int mi = 0; mi < 2; ++mi) {
        mrun[mi] = (f32x4){-1e30f, -1e30f, -1e30f, -1e30f};
        lrun[mi] = (f32x4){0.f, 0.f, 0.f, 0.f};
        #pragma unroll
        for (int ont = 0; ont < 4; ++ont) o[mi][ont] = (f32x4){0.f, 0.f, 0.f, 0.f};
    }

    for (int kv0 = 0; kv0 < SEQ; kv0 += 128) {
        __syncthreads();
        #pragma unroll
        for (int it = 0; it < 4; ++it) {   // K tile: 128 keys x 8 chunks
            int c = it * 256 + tid;
            int key = c >> 3, dg = c & 7;
            *(uint4v*)&Ks[key * 72 + dg * 8] =
                *(const uint4v*)(Kbase + (size_t)(kv0 + key) * QKVN + dg * 8);
        }
        #pragma unroll
        for (int it = 0; it < 4; ++it) {   // Vt tile: 64 d x 16 chunks
            int c = it * 256 + tid;
            int d = c >> 4, kg = c & 15;
            *(uint4v*)&Vs[d * 136 + kg * 8] =
                *(const uint4v*)(Vtb + (size_t)d * SEQ + kv0 + kg * 8);
        }
        __syncthreads();

        // S = Qs * K^T  (C: row=quad*4+i -> q, col=lane&15 -> key)
        f32x4 s[2][8];
        #pragma unroll
        for (int mi = 0; mi < 2; ++mi)
            #pragma unroll
            for (int nt = 0; nt < 8; ++nt) s[mi][nt] = (f32x4){0.f, 0.f, 0.f, 0.f};
        #pragma unroll
        for (int nt = 0; nt < 8; ++nt) {
            short8 kf0 = *(const short8*)&Ks[(nt * 16 + lrow) * 72 + quad * 8];
            short8 kf1 = *(const short8*)&Ks[(nt * 16 + lrow) * 72 + 32 + quad * 8];
            #pragma unroll
            for (int mi = 0; mi < 2; ++mi) {
                s[mi][nt] = __builtin_amdgcn_mfma_f32_16x16x32_bf16(qf[mi][0], kf0, s[mi][nt], 0, 0, 0);
                s[mi][nt] = __builtin_amdgcn_mfma_f32_16x16x32_bf16(qf[mi][1], kf1, s[mi][nt], 0, 0, 0);
            }
        }

        // online softmax per 16-row tile (stats per component i = row quad*4+i)
        #pragma unroll
        for (int mi = 0; mi < 2; ++mi) {
            f32x4 mx = s[mi][0];
            #pragma unroll
            for (int nt = 1; nt < 8; ++nt)
                #pragma unroll
                for (int c2 = 0; c2 < 4; ++c2) mx[c2] = fmaxf(mx[c2], s[mi][nt][c2]);
            #pragma unroll
            for (int off = 1; off < 16; off <<= 1)
                #pragma unroll
                for (int c2 = 0; c2 < 4; ++c2) mx[c2] = fmaxf(mx[c2], __shfl_xor(mx[c2], off));
            f32x4 mnew, alpha;
            #pragma unroll
            for (int c2 = 0; c2 < 4; ++c2) {
                mnew[c2] = fmaxf(mrun[mi][c2], mx[c2]);
                alpha[c2] = __expf(mrun[mi][c2] - mnew[c2]);
            }
            f32x4 rs = (f32x4){0.f, 0.f, 0.f, 0.f};
            #pragma unroll
            for (int nt = 0; nt < 8; ++nt)
                #pragma unroll
                for (int c2 = 0; c2 < 4; ++c2) {
                    float p = __expf(s[mi][nt][c2] - mnew[c2]);
                    s[mi][nt][c2] = p;
                    rs[c2] += p;
                }
            #pragma unroll
            for (int off = 1; off < 16; off <<= 1)
                #pragma unroll
                for (int c2 = 0; c2 < 4; ++c2) rs[c2] += __shfl_xor(rs[c2], off);
            #pragma unroll
            for (int c2 = 0; c2 < 4; ++c2) {
                lrun[mi][c2] = lrun[mi][c2] * alpha[c2] + rs[c2];
            }
            mrun[mi] = mnew;
            #pragma unroll
            for (int ont = 0; ont < 4; ++ont)
                #pragma unroll
                for (int c2 = 0; c2 < 4; ++c2) o[mi][ont][c2] *= alpha[c2];
            // P -> LDS (C-layout) so it can be re-read in A-operand layout
            #pragma unroll
            for (int nt = 0; nt < 8; ++nt)
                #pragma unroll
                for (int c2 = 0; c2 < 4; ++c2)
                    Ps[wave][(mi * 16 + quad * 4 + c2) * 136 + nt * 16 + lrow] = f2bf(s[mi][nt][c2]);
        }

        // O += P * V
        #pragma unroll
        for (int kc4 = 0; kc4 < 4; ++kc4) {
            short8 af0 = *(const short8*)&Ps[wave][(lrow) * 136 + kc4 * 32 + quad * 8];
            short8 af1 = *(const short8*)&Ps[wave][(16 + lrow) * 136 + kc4 * 32 + quad * 8];
            #pragma unroll
            for (int ont = 0; ont < 4; ++ont) {
                short8 vf = *(const short8*)&Vs[(ont * 16 + lrow) * 136 + kc4 * 32 + quad * 8];
                o[0][ont] = __builtin_amdgcn_mfma_f32_16x16x32_bf16(af0, vf, o[0][ont], 0, 0, 0);
                o[1][ont] = __builtin_amdgcn_mfma_f32_16x16x32_bf16(af1, vf, o[1][ont], 0, 0, 0);
            }
        }
    }

    #pragma unroll
    for (int mi = 0; mi < 2; ++mi) {
        f32x4 inv;
        #pragma unroll
        for (int c2 = 0; c2 < 4; ++c2) inv[c2] = 1.0f / lrun[mi][c2];
        #pragma unroll
        for (int ont = 0; ont < 4; ++ont)
            #pragma unroll
            for (int c2 = 0; c2 < 4; ++c2) {
                size_t row = (size_t)(b * SEQ + q0 + mi * 16 + quad * 4 + c2);
                Emb[row * DIMW + h * 64 + ont * 16 + lrow] = f2bf(o[mi][ont][c2] * inv[c2]);
            }
    }
}

extern "C" void kernel_launch(void* const* d_in, const int* in_sizes, int n_in,
                              void* d_out, int out_size, void* d_ws, size_t ws_size,
                              hipStream_t stream)
{
    const float* x  = (const float*)d_in[0];
    const float* Wq = (const float*)d_in[1];
    const float* bq = (const float*)d_in[2];
    const float* Wk = (const float*)d_in[3];
    const float* bk = (const float*)d_in[4];
    const float* Wv = (const float*)d_in[5];
    const float* bv = (const float*)d_in[6];
    const float* Wo = (const float*)d_in[7];
    const float* bo = (const float*)d_in[8];
    float* out = (float*)d_out;
    char* ws = (char*)d_ws;

    unsigned short* Xbf   = (unsigned short*)(ws);               // 8 MB
    unsigned short* Wqkvt = (unsigned short*)(ws + 8388608);     // 6 MB
    unsigned short* Wot   = (unsigned short*)(ws + 14680064);    // 2 MB
    unsigned short* Cqkv  = (unsigned short*)(ws + 16777216);    // 24 MB
    unsigned short* Vt    = (unsigned short*)(ws + 41943040);    // 8 MB
    unsigned short* Emb   = (unsigned short*)(ws + 50331648);    // 8 MB (total 56 MB)

    cast_x_kernel<<<2048, 256, 0, stream>>>(x, Xbf);
    prep_w_kernel<<<dim3(16, 16, 4), 256, 0, stream>>>(Wq, Wk, Wv, Wo, Wqkvt, Wot);
    gemm_bt_kernel<true, unsigned short><<<dim3(24, 32), 256, 0, stream>>>(
        Xbf, Wqkvt, bq, bk, bv, Cqkv, MTOK, QKVN, DIMW);
    vt_kernel<<<dim3(32, 16, 2), 256, 0, stream>>>(Cqkv, Vt);
    attn_kernel<<<dim3(16, 16, 2), 256, 0, stream>>>(Cqkv, Vt, Emb);
    gemm_bt_kernel<false, float><<<dim3(8, 32), 256, 0, stream>>>(
        Emb, Wot, bo, nullptr, nullptr, out, MTOK, DIMW, DIMW);
}

// Round 2
// 256.259 us; speedup vs baseline: 1.0323x; 1.0323x over previous
//
#include <hip/hip_runtime.h>
#include <hip/hip_bf16.h>
#include <stdint.h>

typedef __attribute__((ext_vector_type(8))) short short8;     // 8 bf16 (4 VGPRs)
typedef __attribute__((ext_vector_type(4))) float f32x4;      // MFMA C/D
typedef __attribute__((ext_vector_type(4))) unsigned int uint4v; // 16B copy

#define DIMW 1024
#define HEADS 16
#define HEAD_DIM 64
#define SEQ 2048
#define BATCH 2
#define MTOK 4096
#define QKVN 3072
// 0.125 * log2(e): folds score scale AND exp->exp2 conversion into Q
#define QSCALE 0.1803368801111204f

typedef const __attribute__((address_space(1))) unsigned int* gas_u32p;
typedef __attribute__((address_space(3))) unsigned int* las_u32p;

static __device__ __forceinline__ void gl_lds16(const void* g, void* l) {
    __builtin_amdgcn_global_load_lds((gas_u32p)g, (las_u32p)l, 16, 0, 0);
}

static __device__ __forceinline__ unsigned short f2bf(float f) {
    unsigned int u = __float_as_uint(f);
    u += 0x7fffu + ((u >> 16) & 1u);   // RNE; inputs are finite
    return (unsigned short)(u >> 16);
}

// ---------------- x: fp32 -> bf16 ----------------
__global__ void cast_x_kernel(const float* __restrict__ x, unsigned short* __restrict__ out) {
    int i = (blockIdx.x * 256 + threadIdx.x) * 8;
    float4 a = *(const float4*)(x + i);
    float4 b = *(const float4*)(x + i + 4);
    unsigned short t[8] = { f2bf(a.x), f2bf(a.y), f2bf(a.z), f2bf(a.w),
                            f2bf(b.x), f2bf(b.y), f2bf(b.z), f2bf(b.w) };
    *(uint4v*)(out + i) = *(const uint4v*)t;
}

// ---------------- W [K,N] fp32 -> Wt [N,K] bf16 (Wq|Wk|Wv fused, Wo separate) ----------------
__global__ void prep_w_kernel(const float* __restrict__ Wq, const float* __restrict__ Wk,
                              const float* __restrict__ Wv, const float* __restrict__ Wo,
                              unsigned short* __restrict__ Wqkv_t, unsigned short* __restrict__ Wo_t) {
    __shared__ float tile[64][68];
    int z = blockIdx.z;
    const float* W = (z == 0) ? Wq : (z == 1) ? Wk : (z == 2) ? Wv : Wo;
    unsigned short* out = (z < 3) ? (Wqkv_t + (size_t)z * DIMW * DIMW) : Wo_t;
    int n0 = blockIdx.x * 64, k0 = blockIdx.y * 64;
    int tid = threadIdx.x;
    for (int it = 0; it < 4; ++it) {
        int c = it * 256 + tid;
        int r = c >> 4, cg = c & 15;
        float4 v = *(const float4*)(W + (size_t)(k0 + r) * DIMW + n0 + cg * 4);
        tile[r][cg * 4 + 0] = v.x; tile[r][cg * 4 + 1] = v.y;
        tile[r][cg * 4 + 2] = v.z; tile[r][cg * 4 + 3] = v.w;
    }
    __syncthreads();
    for (int it = 0; it < 2; ++it) {
        int c = it * 256 + tid;
        int n = c >> 3, kg = c & 7;
        unsigned short tmp[8];
        #pragma unroll
        for (int j = 0; j < 8; ++j) tmp[j] = f2bf(tile[kg * 8 + j][n]);
        *(uint4v*)(out + (size_t)(n0 + n) * DIMW + k0 + kg * 8) = *(const uint4v*)tmp;
    }
}

// ---------------- GEMM: C[M,N] = A[M,K](bf16) * Bt[N,K]^T + bias ----------------
// m97 pattern: unpadded 128x32 LDS tiles, global_load_lds width=16.
// QKV3: N=3072; bias b0/b1/b2 per 1024-col section; Q section scaled by QSCALE;
//       V section (sel==2) written transposed+packed to Vt[b*1024+vcol][s].
template<bool QKV3, typename TO>
__global__ __launch_bounds__(256, 3) void gemm_bt_kernel(
    const unsigned short* __restrict__ A, const unsigned short* __restrict__ Bt,
    const float* __restrict__ b0, const float* __restrict__ b1, const float* __restrict__ b2,
    TO* __restrict__ C, unsigned short* __restrict__ Vt, int M, int N, int K)
{
    __shared__ __align__(16) unsigned short As[128 * 32];
    __shared__ __align__(16) unsigned short Bs[128 * 32];
    int tid = threadIdx.x;
    int wave = tid >> 6, lane = tid & 63;
    int lrow = lane & 15, quad = lane >> 4;
    int bm = blockIdx.y * 128, bn = blockIdx.x * 128;
    int wm = (wave >> 1) * 64, wn = (wave & 1) * 64;
    f32x4 acc[4][4];
    #pragma unroll
    for (int i = 0; i < 4; ++i)
        #pragma unroll
        for (int j = 0; j < 4; ++j) acc[i][j] = (f32x4){0.f, 0.f, 0.f, 0.f};
    const unsigned short* Ap = A + (size_t)bm * K;
    const unsigned short* Bp = Bt + (size_t)bn * K;
    int row0 = tid >> 2, cg0 = tid & 3;          // chunk for it=0
    int row1 = (256 + tid) >> 2;                 // chunk for it=1 (cg same)
    for (int k0 = 0; k0 < K; k0 += 32) {
        __syncthreads();
        gl_lds16(Ap + (size_t)row0 * K + k0 + cg0 * 8, &As[tid * 8]);
        gl_lds16(Ap + (size_t)row1 * K + k0 + cg0 * 8, &As[(256 + tid) * 8]);
        gl_lds16(Bp + (size_t)row0 * K + k0 + cg0 * 8, &Bs[tid * 8]);
        gl_lds16(Bp + (size_t)row1 * K + k0 + cg0 * 8, &Bs[(256 + tid) * 8]);
        __syncthreads();   // drains vmcnt (compiler emits full waitcnt before s_barrier)
        short8 af[4], bfr[4];
        #pragma unroll
        for (int mi = 0; mi < 4; ++mi)
            af[mi] = *(const short8*)&As[(wm + mi * 16 + lrow) * 32 + quad * 8];
        #pragma unroll
        for (int ni = 0; ni < 4; ++ni)
            bfr[ni] = *(const short8*)&Bs[(wn + ni * 16 + lrow) * 32 + quad * 8];
        #pragma unroll
        for (int mi = 0; mi < 4; ++mi)
            #pragma unroll
            for (int ni = 0; ni < 4; ++ni)
                acc[mi][ni] = __builtin_amdgcn_mfma_f32_16x16x32_bf16(af[mi], bfr[ni], acc[mi][ni], 0, 0, 0);
    }
    #pragma unroll
    for (int ni = 0; ni < 4; ++ni) {
        int n = bn + wn + ni * 16 + lrow;
        float bias, scale;
        int sel = 0;
        if (QKV3) {
            sel = n >> 10;
            const float* bp = (sel == 0) ? b0 : (sel == 1) ? b1 : b2;
            bias = bp[n & 1023];
            scale = (sel == 0) ? QSCALE : 1.0f;
        } else { bias = b0[n]; scale = 1.0f; }
        #pragma unroll
        for (int mi = 0; mi < 4; ++mi) {
            int m0 = bm + wm + mi * 16 + quad * 4;   // C/D: row=quad*4+reg, col=lane&15
            if (QKV3 && sel == 2) {
                // V: store transposed+packed -> Vt[(b*1024 + vcol)][s], 4 consecutive s
                int vcol = n - 2048;
                int bb = m0 >> 11, s0 = m0 & 2047;
                unsigned short t[4];
                #pragma unroll
                for (int i = 0; i < 4; ++i) t[i] = f2bf(acc[mi][ni][i] + bias);
                *(uint2*)(Vt + ((size_t)(bb * 1024 + vcol)) * SEQ + s0) = *(const uint2*)t;
            } else {
                #pragma unroll
                for (int i = 0; i < 4; ++i) {
                    float val = (acc[mi][ni][i] + bias) * scale;
                    if constexpr (sizeof(TO) == 2) C[(size_t)(m0 + i) * N + n] = (TO)f2bf(val);
                    else                           C[(size_t)(m0 + i) * N + n] = val;
                }
            }
        }
    }
}

// ---------------- flash attention: 4 waves x 32 queries, 128-key stages ----------------
// S^T trick: A=K, B=Q  =>  D[key][q]: lane holds 4 consecutive keys for one q.
__global__ __launch_bounds__(256, 3) void attn_kernel(
    const unsigned short* __restrict__ QKV, const unsigned short* __restrict__ Vt,
    unsigned short* __restrict__ Emb)
{
    __shared__ __align__(16) unsigned short Ks[128 * 72];    // [key][d], pad 72
    __shared__ __align__(16) unsigned short Vs[64 * 136];    // [d][key], pad 136
    __shared__ __align__(16) unsigned short Ps[4][32 * 72];  // per-wave [q][key-half], pad 72
    int tid = threadIdx.x;
    int wave = tid >> 6, lane = tid & 63;
    int lrow = lane & 15, quad = lane >> 4;
    int h = blockIdx.x, qblk = blockIdx.y, b = blockIdx.z;   // x=h: same-head blocks -> same XCD
    int q0 = qblk * 128 + wave * 32;
    const unsigned short* Qbase = QKV + (size_t)(b * SEQ) * QKVN + h * 64;
    const unsigned short* Kbase = QKV + (size_t)(b * SEQ) * QKVN + 1024 + h * 64;
    const unsigned short* Vtb = Vt + (size_t)(b * 1024 + h * 64) * SEQ;

    short8 qf[2][2];   // B-frag: n=lane&15 (q), k=quad*8+j (d)
    #pragma unroll
    for (int mi = 0; mi < 2; ++mi)
        #pragma unroll
        for (int kc = 0; kc < 2; ++kc)
            qf[mi][kc] = *(const short8*)(Qbase + (size_t)(q0 + mi * 16 + lrow) * QKVN + kc * 32 + quad * 8);

    f32x4 o[2][4];
    float mrun[2] = {-1e30f, -1e30f};   // col-domain: per q = lane&15 (base-2)
    float lrun[2] = {0.f, 0.f};
    #pragma unroll
    for (int mi = 0; mi < 2; ++mi)
        #pragma unroll
        for (int ont = 0; ont < 4; ++ont) o[mi][ont] = (f32x4){0.f, 0.f, 0.f, 0.f};

    for (int kv0 = 0; kv0 < SEQ; kv0 += 128) {
        __syncthreads();
        #pragma unroll
        for (int it = 0; it < 4; ++it) {   // K tile: 128 keys x 8 chunks
            int c = it * 256 + tid;
            int key = c >> 3, dg = c & 7;
            *(uint4v*)&Ks[key * 72 + dg * 8] =
                *(const uint4v*)(Kbase + (size_t)(kv0 + key) * QKVN + dg * 8);
        }
        #pragma unroll
        for (int it = 0; it < 4; ++it) {   // Vt tile: 64 d x 16 chunks
            int c = it * 256 + tid;
            int d = c >> 4, kg = c & 15;
            *(uint4v*)&Vs[d * 136 + kg * 8] =
                *(const uint4v*)(Vtb + (size_t)d * SEQ + kv0 + kg * 8);
        }
        __syncthreads();

        // S^T = K * Q^T  (C: row=quad*4+i -> key, col=lane&15 -> q)
        f32x4 s[2][8];
        #pragma unroll
        for (int mi = 0; mi < 2; ++mi)
            #pragma unroll
            for (int nt = 0; nt < 8; ++nt) s[mi][nt] = (f32x4){0.f, 0.f, 0.f, 0.f};
        #pragma unroll
        for (int nt = 0; nt < 8; ++nt) {
            short8 kf0 = *(const short8*)&Ks[(nt * 16 + lrow) * 72 + quad * 8];
            short8 kf1 = *(const short8*)&Ks[(nt * 16 + lrow) * 72 + 32 + quad * 8];
            #pragma unroll
            for (int mi = 0; mi < 2; ++mi) {
                s[mi][nt] = __builtin_amdgcn_mfma_f32_16x16x32_bf16(kf0, qf[mi][0], s[mi][nt], 0, 0, 0);
                s[mi][nt] = __builtin_amdgcn_mfma_f32_16x16x32_bf16(kf1, qf[mi][1], s[mi][nt], 0, 0, 0);
            }
        }

        // online softmax (base-2; stats are scalar per lane in col-domain)
        float arow[2][4];   // row-domain alpha for O rescale
        #pragma unroll
        for (int mi = 0; mi < 2; ++mi) {
            float mx = -1e30f;
            #pragma unroll
            for (int nt = 0; nt < 8; ++nt)
                #pragma unroll
                for (int c2 = 0; c2 < 4; ++c2) mx = fmaxf(mx, s[mi][nt][c2]);
            mx = fmaxf(mx, __shfl_xor(mx, 16));
            mx = fmaxf(mx, __shfl_xor(mx, 32));
            float mnew = fmaxf(mrun[mi], mx);
            float alpha = __builtin_amdgcn_exp2f(mrun[mi] - mnew);
            float rs = 0.f;
            #pragma unroll
            for (int nt = 0; nt < 8; ++nt)
                #pragma unroll
                for (int c2 = 0; c2 < 4; ++c2) {
                    float p = __builtin_amdgcn_exp2f(s[mi][nt][c2] - mnew);
                    s[mi][nt][c2] = p;
                    rs += p;
                }
            rs += __shfl_xor(rs, 16);
            rs += __shfl_xor(rs, 32);
            lrun[mi] = lrun[mi] * alpha + rs;
            mrun[mi] = mnew;
            #pragma unroll
            for (int c2 = 0; c2 < 4; ++c2)
                arow[mi][c2] = __shfl(alpha, quad * 4 + c2);   // col- -> row-domain
            #pragma unroll
            for (int ont = 0; ont < 4; ++ont)
                #pragma unroll
                for (int c2 = 0; c2 < 4; ++c2) o[mi][ont][c2] *= arow[mi][c2];
        }

        // P -> LDS (b64 packed, [q][key]) then PV, in two 64-key phases
        #pragma unroll
        for (int half = 0; half < 2; ++half) {
            #pragma unroll
            for (int mi = 0; mi < 2; ++mi)
                #pragma unroll
                for (int nt2 = 0; nt2 < 4; ++nt2) {
                    int nt = half * 4 + nt2;
                    __hip_bfloat162 p01 = __float22bfloat162_rn(float2{s[mi][nt][0], s[mi][nt][1]});
                    __hip_bfloat162 p23 = __float22bfloat162_rn(float2{s[mi][nt][2], s[mi][nt][3]});
                    uint2 pk;
                    pk.x = *reinterpret_cast<unsigned int*>(&p01);
                    pk.y = *reinterpret_cast<unsigned int*>(&p23);
                    *(uint2*)&Ps[wave][(mi * 16 + lrow) * 72 + nt2 * 16 + quad * 4] = pk;
                }
            #pragma unroll
            for (int kc2 = 0; kc2 < 2; ++kc2) {
                int kc4 = half * 2 + kc2;
                short8 af0 = *(const short8*)&Ps[wave][lrow * 72 + kc2 * 32 + quad * 8];
                short8 af1 = *(const short8*)&Ps[wave][(16 + lrow) * 72 + kc2 * 32 + quad * 8];
                #pragma unroll
                for (int ont = 0; ont < 4; ++ont) {
                    short8 vf = *(const short8*)&Vs[(ont * 16 + lrow) * 136 + kc4 * 32 + quad * 8];
                    o[0][ont] = __builtin_amdgcn_mfma_f32_16x16x32_bf16(af0, vf, o[0][ont], 0, 0, 0);
                    o[1][ont] = __builtin_amdgcn_mfma_f32_16x16x32_bf16(af1, vf, o[1][ont], 0, 0, 0);
                }
            }
        }
    }

    #pragma unroll
    for (int mi = 0; mi < 2; ++mi) {
        float inv[4];
        #pragma unroll
        for (int c2 = 0; c2 < 4; ++c2)
            inv[c2] = 1.0f / __shfl(lrun[mi], quad * 4 + c2);   // row-domain l
        #pragma unroll
        for (int ont = 0; ont < 4; ++ont)
            #pragma unroll
            for (int c2 = 0; c2 < 4; ++c2) {
                size_t row = (size_t)(b * SEQ + q0 + mi * 16 + quad * 4 + c2);
                Emb[row * DIMW + h * 64 + ont * 16 + lrow] = f2bf(o[mi][ont][c2] * inv[c2]);
            }
    }
}

extern "C" void kernel_launch(void* const* d_in, const int* in_sizes, int n_in,
                              void* d_out, int out_size, void* d_ws, size_t ws_size,
                              hipStream_t stream)
{
    const float* x  = (const float*)d_in[0];
    const float* Wq = (const float*)d_in[1];
    const float* bq = (const float*)d_in[2];
    const float* Wk = (const float*)d_in[3];
    const float* bk = (const float*)d_in[4];
    const float* Wv = (const float*)d_in[5];
    const float* bv = (const float*)d_in[6];
    const float* Wo = (const float*)d_in[7];
    const float* bo = (const float*)d_in[8];
    float* out = (float*)d_out;
    char* ws = (char*)d_ws;

    unsigned short* Xbf   = (unsigned short*)(ws);               // 8 MB
    unsigned short* Wqkvt = (unsigned short*)(ws + 8388608);     // 6 MB
    unsigned short* Wot   = (unsigned short*)(ws + 14680064);    // 2 MB
    unsigned short* Cqkv  = (unsigned short*)(ws + 16777216);    // 24 MB (Q,K used)
    unsigned short* Vt    = (unsigned short*)(ws + 41943040);    // 8 MB
    unsigned short* Emb   = (unsigned short*)(ws + 50331648);    // 8 MB (total 56 MB)

    cast_x_kernel<<<2048, 256, 0, stream>>>(x, Xbf);
    prep_w_kernel<<<dim3(16, 16, 4), 256, 0, stream>>>(Wq, Wk, Wv, Wo, Wqkvt, Wot);
    gemm_bt_kernel<true, unsigned short><<<dim3(24, 32), 256, 0, stream>>>(
        Xbf, Wqkvt, bq, bk, bv, Cqkv, Vt, MTOK, QKVN, DIMW);
    attn_kernel<<<dim3(16, 16, 2), 256, 0, stream>>>(Cqkv, Vt, Emb);
    gemm_bt_kernel<false, float><<<dim3(8, 32), 256, 0, stream>>>(
        Emb, Wot, bo, nullptr, nullptr, out, nullptr, MTOK, DIMW, DIMW);
}